// Round 13
// baseline (5833.140 us; speedup 1.0000x reference)
//
#include <hip/hip_runtime.h>

#define NHID   128
#define NSTEPS 512
#define NSAMP  4096
#define SPB    16
#define BS     512
#define NBLK   (NSAMP / SPB)          // 256 blocks, 1 per CU
#define KL     22                     // k4-chunks of W staged in LDS (of 32)
#define SAMP_ELEMS (NSAMP * NSTEPS)
#define PLANE_V4   (32 * 128)         // v4f per plane
#define WPK_FLOATS (3 * PLANE_V4 * 4) // 49152 floats = 192 KB

typedef float v2f __attribute__((ext_vector_type(2)));
typedef float v4f __attribute__((ext_vector_type(4)));

// scalar fma with h in a 32-bit SGPR (VOP3 allows one SGPR source)
#define FMA_S(ACC, W, HS) \
    asm("v_fma_f32 %0, %1, %2, %0" : "+v"(ACC) : "v"(W), "s"(HS))

template<int IMM>
__device__ __forceinline__ float swz(float x) {
    return __int_as_float(__builtin_amdgcn_ds_swizzle(__float_as_int(x), IMM));
}

// Three planes, each [k4][c] of v4f (16B per (k4,c), contiguous across c):
//   pA[k4][c] = (wz[4k4],   wr[4k4],   wz[4k4+1], wr[4k4+1]) (c)
//   pB[k4][c] = (wz[4k4+2], wr[4k4+2], wz[4k4+3], wr[4k4+3]) (c)
//   pH[k4][c] = (wh[4k4], wh[4k4+1], wh[4k4+2], wh[4k4+3]) (c)
__global__ __launch_bounds__(256)
void pack_w_kernel(const float* __restrict__ rk, float* __restrict__ ws) {
    const int i = blockIdx.x * 256 + threadIdx.x;
    if (i >= WPK_FLOATS) return;
    const int plane = i / (PLANE_V4 * 4);
    const int r     = i - plane * (PLANE_V4 * 4);
    const int e  = r & 3;
    const int c  = (r >> 2) & 127;
    const int k4 = r >> 9;
    float v;
    if (plane == 2) {
        v = rk[(4 * k4 + e) * 384 + 256 + c];
    } else {
        const int koff = plane * 2 + (e >> 1);
        const int gate = e & 1;                  // 0=z, 1=r
        v = rk[(4 * k4 + koff) * 384 + gate * NHID + c];
    }
    ws[i] = v;
}

// one k: 4 readlane + 12 scalar fma (SGPR h); chains bias-init + k-ascending
#define K1(WZ, WR, WH, HSRC, L) do {                                     \
    const int h0_ = __builtin_amdgcn_readlane(__float_as_int((HSRC).x), (L)); \
    const int h1_ = __builtin_amdgcn_readlane(__float_as_int((HSRC).y), (L)); \
    const int h2_ = __builtin_amdgcn_readlane(__float_as_int((HSRC).z), (L)); \
    const int h3_ = __builtin_amdgcn_readlane(__float_as_int((HSRC).w), (L)); \
    FMA_S(az0, WZ, h0_); FMA_S(ar0, WR, h0_); FMA_S(ah0, WH, h0_);       \
    FMA_S(az1, WZ, h1_); FMA_S(ar1, WR, h1_); FMA_S(ah1, WH, h1_);       \
    FMA_S(az2, WZ, h2_); FMA_S(ar2, WR, h2_); FMA_S(ah2, WH, h2_);       \
    FMA_S(az3, WZ, h3_); FMA_S(ar3, WR, h3_); FMA_S(ah3, WH, h3_);       \
} while (0)

#define K4STEP(HSRC, LB, ZRA, ZRB, WHQ) do {                             \
    K1((ZRA).x, (ZRA).y, (WHQ).x, HSRC, (LB) + 0);                       \
    K1((ZRA).z, (ZRA).w, (WHQ).y, HSRC, (LB) + 1);                       \
    K1((ZRB).x, (ZRB).y, (WHQ).z, HSRC, (LB) + 2);                       \
    K1((ZRB).z, (ZRB).w, (WHQ).w, HSRC, (LB) + 3);                       \
} while (0)

template<int TR>
__global__ __launch_bounds__(BS, 2)
void vmc_gru_kernel(const float* __restrict__ gk,   // (2, 384)
                    const float* __restrict__ rk,   // (128, 384)
                    const float* __restrict__ gb,   // (2, 384)
                    const float* __restrict__ dw,   // (128, 2)
                    const float* __restrict__ db,   // (2,)
                    const float* __restrict__ u,    // (4096, 512)
                    const float* __restrict__ ws,   // packed planes
                    float* __restrict__ out)        // samples then logp
{
    __shared__ v4f   sA[KL * 128];            // 44 KB
    __shared__ v4f   sB[KL * 128];            // 44 KB
    __shared__ v4f   sH[KL * 128];            // 44 KB
    __shared__ float hsm[2][4][NHID][4];      // 16 KB, h[buf][quad][k][4 samples]
    __shared__ float part[2][8][4][8];        // 2 KB

    const int tid  = threadIdx.x;
    const int lane = tid & 63;
    const int wv   = tid >> 6;
    const int half = wv & 1;
    const int q    = wv >> 1;
    const int c    = half * 64 + lane;
    const int sbase = blockIdx.x * SPB + q * 4;

    if (TR) {
        const v4f* g = (const v4f*)ws;
        for (int i = tid; i < KL * 128; i += BS) {
            sA[i] = g[i];
            sB[i] = g[PLANE_V4 + i];
            sH[i] = g[2 * PLANE_V4 + i];
        }
    }
    for (int i = tid; i < 2 * 4 * NHID * 4; i += BS) (&hsm[0][0][0][0])[i] = 0.0f;
    __syncthreads();

    // per-channel constants
    const float brz = gb[384 + c];
    const float brr = gb[384 + 128 + c];
    const float brh = gb[384 + 256 + c];
    const float xzI = gb[c],       xz0c = xzI + gk[c],       xz1c = xzI + gk[384 + c];
    const float xrI = gb[128 + c], xr0c = xrI + gk[128 + c], xr1c = xrI + gk[384 + 128 + c];
    const float xhI = gb[256 + c], xh0c = xhI + gk[256 + c], xh1c = xhI + gk[384 + 256 + c];
    const float dwc0 = dw[c * 2], dwc1 = dw[c * 2 + 1];
    const float db0 = db[0], db1 = db[1];

    const v4f* lA = sA + c;                         // + k4*128
    const v4f* lB = sB + c;
    const v4f* lH = sH + c;
    const v4f* gA = (const v4f*)ws + c;             // + k4*128
    const v4f* gB = (const v4f*)ws + PLANE_V4 + c;
    const v4f* gH = (const v4f*)ws + 2 * PLANE_V4 + c;
    const float* rkc = rk + c;

    int   pv[4] = {0, 0, 0, 0};
    float lg[4] = {0.f, 0.f, 0.f, 0.f};
    float pr[4] = {1.f, 1.f, 1.f, 1.f};
    int cur = 0;

    for (int t = 0; t < NSTEPS; ++t) {
        float uv[4];
        #pragma unroll
        for (int j = 0; j < 4; ++j)
            uv[j] = u[(size_t)(sbase + j) * NSTEPS + t];

        // distributed h: lane l holds h[k=l][quad][4s] (hA), h[k=64+l] (hB)
        const v4f hA = *(const v4f*)&hsm[cur][q][lane][0];
        const v4f hB = *(const v4f*)&hsm[cur][q][64 + lane][0];

        float az0 = brz, az1 = brz, az2 = brz, az3 = brz;
        float ar0 = brr, ar1 = brr, ar2 = brr, ar3 = brr;
        float ah0 = brh, ah1 = brh, ah2 = brh, ah3 = brh;

        if (TR) {
            #pragma unroll 4
            for (int k4 = 0; k4 < 16; ++k4) {          // W LDS, h from hA
                const v4f zrA = lA[k4 * 128];
                const v4f zrB = lB[k4 * 128];
                const v4f whq = lH[k4 * 128];
                K4STEP(hA, k4 * 4, zrA, zrB, whq);
            }
            #pragma unroll 4
            for (int k4 = 16; k4 < KL; ++k4) {         // W LDS, h from hB
                const v4f zrA = lA[k4 * 128];
                const v4f zrB = lB[k4 * 128];
                const v4f whq = lH[k4 * 128];
                K4STEP(hB, k4 * 4 - 64, zrA, zrB, whq);
            }
            #pragma unroll 4
            for (int k4 = KL; k4 < 32; ++k4) {         // W from L1/L2, h from hB
                const v4f zrA = gA[k4 * 128];
                const v4f zrB = gB[k4 * 128];
                const v4f whq = gH[k4 * 128];
                K4STEP(hB, k4 * 4 - 64, zrA, zrB, whq);
            }
        } else {
            #pragma unroll 4
            for (int k = 0; k < NHID; ++k) {
                const v4f hsrc = (k < 64) ? hA : hB;
                const int l = k & 63;
                const int h0_ = __builtin_amdgcn_readlane(__float_as_int(hsrc.x), l);
                const int h1_ = __builtin_amdgcn_readlane(__float_as_int(hsrc.y), l);
                const int h2_ = __builtin_amdgcn_readlane(__float_as_int(hsrc.z), l);
                const int h3_ = __builtin_amdgcn_readlane(__float_as_int(hsrc.w), l);
                const float wzs = rkc[k * 384];
                const float wrs = rkc[k * 384 + 128];
                const float whs = rkc[k * 384 + 256];
                FMA_S(az0, wzs, h0_); FMA_S(ar0, wrs, h0_); FMA_S(ah0, whs, h0_);
                FMA_S(az1, wzs, h1_); FMA_S(ar1, wrs, h1_); FMA_S(ah1, whs, h1_);
                FMA_S(az2, wzs, h2_); FMA_S(ar2, wrs, h2_); FMA_S(ah2, whs, h2_);
                FMA_S(az3, wzs, h3_); FMA_S(ar3, wrs, h3_); FMA_S(ah3, whs, h3_);
            }
        }

        const float az[4] = {az0, az1, az2, az3};
        const float ar[4] = {ar0, ar1, ar2, ar3};
        const float ah[4] = {ah0, ah1, ah2, ah3};

        // ---- gates + state update (h_old for channel c is lane-local)
        const v4f ho = half ? hB : hA;
        const float hov[4] = {ho.x, ho.y, ho.z, ho.w};
        float hn[4], p0s[4], p1s[4];
        #pragma unroll
        for (int j = 0; j < 4; ++j) {
            float xz = pv[j] ? xz1c : xz0c;
            float xr = pv[j] ? xr1c : xr0c;
            float xh = pv[j] ? xh1c : xh0c;
            if (t == 0) { xz = xzI; xr = xrI; xh = xhI; }
            const float z  = 1.0f / (1.0f + expf(-(xz + az[j])));
            const float r  = 1.0f / (1.0f + expf(-(xr + ar[j])));
            const float hc = tanhf(xh + r * ah[j]);
            const float hnew = z * hov[j] + (1.0f - z) * hc;
            hn[j] = hnew;
            p0s[j] = hnew * dwc0;
            p1s[j] = hnew * dwc1;
        }
        *(v4f*)&hsm[cur ^ 1][q][c][0] = (v4f){hn[0], hn[1], hn[2], hn[3]};

        // butterfly over channel bits 0..3 (lane bits 0..3): same tree as R12
        #pragma unroll
        for (int j = 0; j < 4; ++j) {
            p0s[j] += swz<0x041F>(p0s[j]);  p1s[j] += swz<0x041F>(p1s[j]);
            p0s[j] += swz<0x081F>(p0s[j]);  p1s[j] += swz<0x081F>(p1s[j]);
            p0s[j] += swz<0x101F>(p0s[j]);  p1s[j] += swz<0x101F>(p1s[j]);
            p0s[j] += swz<0x201F>(p0s[j]);  p1s[j] += swz<0x201F>(p1s[j]);
        }
        const int pb = t & 1;
        if ((lane & 15) == 0) {
            const int g = lane >> 4;
            *(float4*)&part[pb][wv][g][0] = make_float4(p0s[0], p0s[1], p0s[2], p0s[3]);
            *(float4*)&part[pb][wv][g][4] = make_float4(p1s[0], p1s[1], p1s[2], p1s[3]);
        }
        __syncthreads();   // single barrier: h_new + partials visible

        // ---- fold 8 partials (same order as R12)
        float l0[4] = {db0, db0, db0, db0};
        float l1[4] = {db1, db1, db1, db1};
        #pragma unroll
        for (int w = 0; w < 8; ++w) {
            const int hw = w >> 2, g = w & 3;
            const float4 a = *(const float4*)&part[pb][q * 2 + hw][g][0];
            const float4 b = *(const float4*)&part[pb][q * 2 + hw][g][4];
            l0[0] += a.x; l0[1] += a.y; l0[2] += a.z; l0[3] += a.w;
            l1[0] += b.x; l1[1] += b.y; l1[2] += b.z; l1[3] += b.w;
        }

        // ---- softmax / sample / logp (redundant per thread for its quad)
        #pragma unroll
        for (int j = 0; j < 4; ++j) {
            const float mx = fmaxf(l0[j], l1[j]);
            const float e0 = expf(l0[j] - mx);
            const float e1 = expf(l1[j] - mx);
            const float inv = 1.0f / (e0 + e1);
            const float p1v = e1 * inv;
            const int st = (uv[j] < p1v) ? 1 : 0;
            const float psel = st ? p1v : (e0 * inv);
            pr[j] *= (psel + 1e-10f);
            pv[j] = st;
            if (lane == 0 && half == 0)
                out[(size_t)(sbase + j) * NSTEPS + t] = (float)st;
        }
        if ((t & 7) == 7) {
            #pragma unroll
            for (int j = 0; j < 4; ++j) { lg[j] += logf(pr[j]); pr[j] = 1.0f; }
        }
        cur ^= 1;
    }

    if (lane == 0 && half == 0) {
        #pragma unroll
        for (int j = 0; j < 4; ++j)
            out[SAMP_ELEMS + sbase + j] = lg[j];
    }
}

extern "C" void kernel_launch(void* const* d_in, const int* in_sizes, int n_in,
                              void* d_out, int out_size, void* d_ws, size_t ws_size,
                              hipStream_t stream) {
    const float* gk = (const float*)d_in[0];
    const float* rk = (const float*)d_in[1];
    const float* gb = (const float*)d_in[2];
    const float* dw = (const float*)d_in[3];
    const float* db = (const float*)d_in[4];
    const float* u  = (const float*)d_in[5];
    float* out = (float*)d_out;

    if (ws_size >= (size_t)WPK_FLOATS * sizeof(float)) {
        float* ws = (float*)d_ws;
        pack_w_kernel<<<(WPK_FLOATS + 255) / 256, 256, 0, stream>>>(rk, ws);
        vmc_gru_kernel<1><<<NBLK, BS, 0, stream>>>(gk, rk, gb, dw, db, u, ws, out);
    } else {
        vmc_gru_kernel<0><<<NBLK, BS, 0, stream>>>(gk, rk, gb, dw, db, u, rk, out);
    }
}

// Round 14
// 4276.458 us; speedup vs baseline: 1.3640x; 1.3640x over previous
//
#include <hip/hip_runtime.h>

#define NHID   128
#define NSTEPS 512
#define NSAMP  4096
#define SPB    16
#define BS     512
#define NBLK   (NSAMP / SPB)          // 256 blocks, 1 per CU
#define KL4    6                      // k4-chunks of W staged in LDS (of 32)
#define SAMP_ELEMS (NSAMP * NSTEPS)
#define WT_ELEMS   (3 * NHID * NHID)  // packed weights, 196 KB

typedef float v2f __attribute__((ext_vector_type(2)));
typedef float v4f __attribute__((ext_vector_type(4)));

// packed fma, broadcast LOW half of weight pair to both lanes:
//   acc.lo += w.lo*h.lo ; acc.hi += w.lo*h.hi
#define PK_LO(ACC, W2, H2) \
    asm("v_pk_fma_f32 %0, %1, %2, %0 op_sel:[0,0,0] op_sel_hi:[0,1,1]" \
        : "+v"(ACC) : "v"(W2), "v"(H2))
// broadcast HIGH half of weight pair:
#define PK_HI(ACC, W2, H2) \
    asm("v_pk_fma_f32 %0, %1, %2, %0 op_sel:[1,0,0] op_sel_hi:[1,1,1]" \
        : "+v"(ACC) : "v"(W2), "v"(H2))

template<int IMM>
__device__ __forceinline__ float swz(float x) {
    return __int_as_float(__builtin_amdgcn_ds_swizzle(__float_as_int(x), IMM));
}

// wt[g][k4][c][j] = rk[(4*k4+j)*384 + g*128 + c]
__global__ __launch_bounds__(256)
void pack_w_kernel(const float* __restrict__ rk, float* __restrict__ wt) {
    const int i = blockIdx.x * 256 + threadIdx.x;
    if (i < WT_ELEMS) {
        const int j  = i & 3;
        const int c  = (i >> 2) & 127;
        const int k4 = (i >> 9) & 31;
        const int g  = i >> 14;
        wt[i] = rk[(k4 * 4 + j) * 384 + g * NHID + c];
    }
}

template<int TR>
__global__ __launch_bounds__(BS, 2)
void vmc_gru_kernel(const float* __restrict__ gk,   // (2, 384)
                    const float* __restrict__ rk,   // (128, 384)
                    const float* __restrict__ gb,   // (2, 384)
                    const float* __restrict__ dw,   // (128, 2)
                    const float* __restrict__ db,   // (2,)
                    const float* __restrict__ u,    // (4096, 512)
                    const float* __restrict__ wt,   // packed (3,32,128,4)
                    float* __restrict__ out)        // samples then logp
{
    __shared__ float hsm[2][NHID][SPB];        // 16 KB, double-buffered h[k][s]
    __shared__ float part[2][8][SPB][2];       // 2 KB
    __shared__ float uld[NSTEPS][SPB];         // 32 KB, u transposed
    __shared__ v4f   slds[3 * KL4 * NHID];     // 36 KB, W chunk [g][k4<KL4][c]

    const int tid = threadIdx.x;
    const int cg  = tid >> 2;                // channel 0..127
    const int sq  = tid & 3;                 // sample-quad
    const int s0  = sq * 4;
    const int wv  = tid >> 6;                // wave 0..7

    // ---- stage u transposed
    {
        const int sl = tid >> 5;
        const int t0 = (tid & 31) * 16;
        const float* up = u + (size_t)(blockIdx.x * SPB + sl) * NSTEPS + t0;
        const float4 a = ((const float4*)up)[0];
        const float4 b = ((const float4*)up)[1];
        const float4 c = ((const float4*)up)[2];
        const float4 d = ((const float4*)up)[3];
        const float tmp[16] = {a.x,a.y,a.z,a.w, b.x,b.y,b.z,b.w,
                               c.x,c.y,c.z,c.w, d.x,d.y,d.z,d.w};
        #pragma unroll
        for (int i = 0; i < 16; ++i) uld[t0 + i][sl] = tmp[i];
    }
    // ---- stage first KL4 k4-chunks of W into LDS (once)
    if (TR) {
        const v4f* wt4 = (const v4f*)wt;
        for (int i = tid; i < 3 * KL4 * NHID; i += BS) {
            const int g = i / (KL4 * NHID);
            const int r = i - g * (KL4 * NHID);
            slds[i] = wt4[g * 4096 + r];
        }
    }
    for (int i = tid; i < NHID * SPB; i += BS) (&hsm[0][0][0])[i] = 0.0f;
    __syncthreads();

    const float brz = gb[384 + cg];
    const float brr = gb[384 + 128 + cg];
    const float brh = gb[384 + 256 + cg];
    const float xzI = gb[cg],       xz0c = xzI + gk[cg],       xz1c = xzI + gk[384 + cg];
    const float xrI = gb[128 + cg], xr0c = xrI + gk[128 + cg], xr1c = xrI + gk[384 + 128 + cg];
    const float xhI = gb[256 + cg], xh0c = xhI + gk[256 + cg], xh1c = xhI + gk[384 + 256 + cg];
    const float dwc0 = dw[cg * 2], dwc1 = dw[cg * 2 + 1];
    const float db0 = db[0], db1 = db[1];

    const v4f* lz = slds + cg;                     // LDS planes
    const v4f* lr = slds + KL4 * 128 + cg;
    const v4f* lh = slds + 2 * KL4 * 128 + cg;
    const v4f* wz4 = (const v4f*)wt + cg;          // global planes
    const v4f* wr4 = (const v4f*)wt + 4096 + cg;
    const v4f* wh4 = (const v4f*)wt + 8192 + cg;
    const float* rkp = rk + cg;                    // fallback

    int   pv[4] = {0, 0, 0, 0};
    float lg[4] = {0.f, 0.f, 0.f, 0.f};
    float pr[4] = {1.f, 1.f, 1.f, 1.f};            // 8-step psel product
    int cur = 0;

    for (int t = 0; t < NSTEPS; ++t) {
        v2f az01 = {brz, brz}, az23 = {brz, brz};
        v2f ar01 = {brr, brr}, ar23 = {brr, brr};
        v2f ah01 = {brh, brh}, ah23 = {brh, brh};
        const float* hb = &hsm[cur][0][0];

#define GEMM_K4(WZ, WR, WH, K4) do {                                      \
    const v4f h0 = *(const v4f*)(hb + (4*(K4)+0)*SPB + s0);               \
    const v4f h1 = *(const v4f*)(hb + (4*(K4)+1)*SPB + s0);               \
    const v4f h2 = *(const v4f*)(hb + (4*(K4)+2)*SPB + s0);               \
    const v4f h3 = *(const v4f*)(hb + (4*(K4)+3)*SPB + s0);               \
    const v2f wzA = (WZ).xy, wzB = (WZ).zw;                               \
    const v2f wrA = (WR).xy, wrB = (WR).zw;                               \
    const v2f whA = (WH).xy, whB = (WH).zw;                               \
    PK_LO(az01, wzA, h0.xy); PK_LO(az23, wzA, h0.zw);                     \
    PK_LO(ar01, wrA, h0.xy); PK_LO(ar23, wrA, h0.zw);                     \
    PK_LO(ah01, whA, h0.xy); PK_LO(ah23, whA, h0.zw);                     \
    PK_HI(az01, wzA, h1.xy); PK_HI(az23, wzA, h1.zw);                     \
    PK_HI(ar01, wrA, h1.xy); PK_HI(ar23, wrA, h1.zw);                     \
    PK_HI(ah01, whA, h1.xy); PK_HI(ah23, whA, h1.zw);                     \
    PK_LO(az01, wzB, h2.xy); PK_LO(az23, wzB, h2.zw);                     \
    PK_LO(ar01, wrB, h2.xy); PK_LO(ar23, wrB, h2.zw);                     \
    PK_LO(ah01, whB, h2.xy); PK_LO(ah23, whB, h2.zw);                     \
    PK_HI(az01, wzB, h3.xy); PK_HI(az23, wzB, h3.zw);                     \
    PK_HI(ar01, wrB, h3.xy); PK_HI(ar23, wrB, h3.zw);                     \
    PK_HI(ah01, whB, h3.xy); PK_HI(ah23, whB, h3.zw);                     \
} while (0)

        if (TR) {
            #pragma unroll
            for (int k4 = 0; k4 < KL4; ++k4) {        // LDS-resident chunk
                const v4f wz = lz[k4 * 128];
                const v4f wr = lr[k4 * 128];
                const v4f wh = lh[k4 * 128];
                GEMM_K4(wz, wr, wh, k4);
            }
            #pragma unroll
            for (int k4 = KL4; k4 < 32; ++k4) {       // global chunk (loads hoist, L1-hit)
                const v4f wz = wz4[k4 * 128];
                const v4f wr = wr4[k4 * 128];
                const v4f wh = wh4[k4 * 128];
                GEMM_K4(wz, wr, wh, k4);
            }
        } else {
            const float* wp = rkp;
            #pragma unroll 4
            for (int k = 0; k < NHID; ++k) {
                const float wzs = wp[0];
                const float wrs = wp[NHID];
                const float whs = wp[2 * NHID];
                const v4f hv = *(const v4f*)(hb + k * SPB + s0);
                const float hk[4] = {hv.x, hv.y, hv.z, hv.w};
                float azs[4] = {az01.x, az01.y, az23.x, az23.y};
                float ars[4] = {ar01.x, ar01.y, ar23.x, ar23.y};
                float ahs[4] = {ah01.x, ah01.y, ah23.x, ah23.y};
                #pragma unroll
                for (int j = 0; j < 4; ++j) azs[j] = fmaf(wzs, hk[j], azs[j]);
                #pragma unroll
                for (int j = 0; j < 4; ++j) ars[j] = fmaf(wrs, hk[j], ars[j]);
                #pragma unroll
                for (int j = 0; j < 4; ++j) ahs[j] = fmaf(whs, hk[j], ahs[j]);
                az01 = (v2f){azs[0], azs[1]}; az23 = (v2f){azs[2], azs[3]};
                ar01 = (v2f){ars[0], ars[1]}; ar23 = (v2f){ars[2], ars[3]};
                ah01 = (v2f){ahs[0], ahs[1]}; ah23 = (v2f){ahs[2], ahs[3]};
                wp += 3 * NHID;
            }
        }
#undef GEMM_K4

        const float az[4] = {az01.x, az01.y, az23.x, az23.y};
        const float ar[4] = {ar01.x, ar01.y, ar23.x, ar23.y};
        const float ah[4] = {ah01.x, ah01.y, ah23.x, ah23.y};

        // ---- gates + state update
        const v4f ho = *(const v4f*)(hb + cg * SPB + s0);
        const float hov[4] = {ho.x, ho.y, ho.z, ho.w};
        float hn[4], p0s[4], p1s[4];
        #pragma unroll
        for (int j = 0; j < 4; ++j) {
            float xz = pv[j] ? xz1c : xz0c;
            float xr = pv[j] ? xr1c : xr0c;
            float xh = pv[j] ? xh1c : xh0c;
            if (t == 0) { xz = xzI; xr = xrI; xh = xhI; }
            const float z  = 1.0f / (1.0f + expf(-(xz + az[j])));
            const float r  = 1.0f / (1.0f + expf(-(xr + ar[j])));
            const float hc = tanhf(xh + r * ah[j]);
            const float hnew = z * hov[j] + (1.0f - z) * hc;
            hn[j] = hnew;
            p0s[j] = hnew * dwc0;
            p1s[j] = hnew * dwc1;
        }
        *(v4f*)&hsm[cur ^ 1][cg][s0] = (v4f){hn[0], hn[1], hn[2], hn[3]};

        // butterfly over 16 channels: xor 4,8,16 via ds_swizzle imm, xor 32 via shfl
        #pragma unroll
        for (int j = 0; j < 4; ++j) {
            p0s[j] += swz<0x101F>(p0s[j]);  p1s[j] += swz<0x101F>(p1s[j]);
            p0s[j] += swz<0x201F>(p0s[j]);  p1s[j] += swz<0x201F>(p1s[j]);
            p0s[j] += swz<0x401F>(p0s[j]);  p1s[j] += swz<0x401F>(p1s[j]);
            p0s[j] += __shfl_xor(p0s[j], 32);
            p1s[j] += __shfl_xor(p1s[j], 32);
        }
        const int pb = t & 1;
        if ((tid & 63) < 4) {
            *(float4*)&part[pb][wv][s0][0]     = make_float4(p0s[0], p1s[0], p0s[1], p1s[1]);
            *(float4*)&part[pb][wv][s0 + 2][0] = make_float4(p0s[2], p1s[2], p0s[3], p1s[3]);
        }
        __syncthreads();   // single barrier: h_new + partials visible

        // ---- redundant logit/sample phase: every thread, its own 4 samples
        float l0[4] = {db0, db0, db0, db0};
        float l1[4] = {db1, db1, db1, db1};
        #pragma unroll
        for (int w = 0; w < 8; ++w) {
            const float4 qa = *(const float4*)&part[pb][w][s0][0];
            const float4 qb = *(const float4*)&part[pb][w][s0 + 2][0];
            l0[0] += qa.x; l1[0] += qa.y;
            l0[1] += qa.z; l1[1] += qa.w;
            l0[2] += qb.x; l1[2] += qb.y;
            l0[3] += qb.z; l1[3] += qb.w;
        }
        const float4 uu = *(const float4*)&uld[t][s0];
        const float uv[4] = {uu.x, uu.y, uu.z, uu.w};
        #pragma unroll
        for (int j = 0; j < 4; ++j) {
            const float mx = fmaxf(l0[j], l1[j]);
            const float e0 = expf(l0[j] - mx);
            const float e1 = expf(l1[j] - mx);
            const float inv = 1.0f / (e0 + e1);
            const float p1v = e1 * inv;
            const int st = (uv[j] < p1v) ? 1 : 0;
            const float psel = st ? p1v : (e0 * inv);
            pr[j] *= (psel + 1e-10f);
            pv[j] = st;
            if (cg == 0)
                out[(size_t)(blockIdx.x * SPB + s0 + j) * NSTEPS + t] = (float)st;
        }
        if ((t & 7) == 7) {     // batched log: log(prod) == sum(log) up to rounding
            #pragma unroll
            for (int j = 0; j < 4; ++j) { lg[j] += logf(pr[j]); pr[j] = 1.0f; }
        }
        cur ^= 1;
    }

    if (cg == 0) {
        #pragma unroll
        for (int j = 0; j < 4; ++j)
            out[SAMP_ELEMS + blockIdx.x * SPB + s0 + j] = lg[j];
    }
}

extern "C" void kernel_launch(void* const* d_in, const int* in_sizes, int n_in,
                              void* d_out, int out_size, void* d_ws, size_t ws_size,
                              hipStream_t stream) {
    const float* gk = (const float*)d_in[0];
    const float* rk = (const float*)d_in[1];
    const float* gb = (const float*)d_in[2];
    const float* dw = (const float*)d_in[3];
    const float* db = (const float*)d_in[4];
    const float* u  = (const float*)d_in[5];
    float* out = (float*)d_out;

    if (ws_size >= (size_t)WT_ELEMS * sizeof(float)) {
        float* wt = (float*)d_ws;
        pack_w_kernel<<<(WT_ELEMS + 255) / 256, 256, 0, stream>>>(rk, wt);
        vmc_gru_kernel<1><<<NBLK, BS, 0, stream>>>(gk, rk, gb, dw, db, u, wt, out);
    } else {
        vmc_gru_kernel<0><<<NBLK, BS, 0, stream>>>(gk, rk, gb, dw, db, u, rk, out);
    }
}

// Round 15
// 4040.222 us; speedup vs baseline: 1.4438x; 1.0585x over previous
//
#include <hip/hip_runtime.h>

#define NHID   128
#define NSTEPS 512
#define NSAMP  4096
#define SPB    8
#define BS     256
#define NBLK   (NSAMP / SPB)          // 512 blocks, 2 per CU
#define KL4    11                     // k4-chunks of W staged in LDS (of 32)
#define SAMP_ELEMS (NSAMP * NSTEPS)
#define WT_ELEMS   (3 * NHID * NHID)  // packed weights, 196 KB

typedef float v2f __attribute__((ext_vector_type(2)));
typedef float v4f __attribute__((ext_vector_type(4)));

// packed fma, broadcast LOW half of weight pair to both lanes:
//   acc.lo += w.lo*h.lo ; acc.hi += w.lo*h.hi
#define PK_LO(ACC, W2, H2) \
    asm("v_pk_fma_f32 %0, %1, %2, %0 op_sel:[0,0,0] op_sel_hi:[0,1,1]" \
        : "+v"(ACC) : "v"(W2), "v"(H2))
// broadcast HIGH half of weight pair:
#define PK_HI(ACC, W2, H2) \
    asm("v_pk_fma_f32 %0, %1, %2, %0 op_sel:[1,0,0] op_sel_hi:[1,1,1]" \
        : "+v"(ACC) : "v"(W2), "v"(H2))

template<int IMM>
__device__ __forceinline__ float swz(float x) {
    return __int_as_float(__builtin_amdgcn_ds_swizzle(__float_as_int(x), IMM));
}

// wt[g][k4][c][j] = rk[(4*k4+j)*384 + g*128 + c]  (same packing as R8)
__global__ __launch_bounds__(256)
void pack_w_kernel(const float* __restrict__ rk, float* __restrict__ wt) {
    const int i = blockIdx.x * 256 + threadIdx.x;
    if (i < WT_ELEMS) {
        const int j  = i & 3;
        const int c  = (i >> 2) & 127;
        const int k4 = (i >> 9) & 31;
        const int g  = i >> 14;
        wt[i] = rk[(k4 * 4 + j) * 384 + g * NHID + c];
    }
}

template<int TR>
__global__ __launch_bounds__(BS, 2)
void vmc_gru_kernel(const float* __restrict__ gk,   // (2, 384)
                    const float* __restrict__ rk,   // (128, 384)
                    const float* __restrict__ gb,   // (2, 384)
                    const float* __restrict__ dw,   // (128, 2)
                    const float* __restrict__ db,   // (2,)
                    const float* __restrict__ u,    // (4096, 512)
                    const float* __restrict__ wt,   // packed (3,32,128,4)
                    float* __restrict__ out)        // samples then logp
{
    __shared__ float hsm[2][NHID][SPB];        // 8 KB, double-buffered h[k][s]
    __shared__ float part[2][4][2][8];         // 512 B: [pb][wave][sq][p0 x4,p1 x4]
    __shared__ v4f   slds[3 * KL4 * NHID];     // 66 KB, W chunk [g][k4<KL4][c]

    const int tid = threadIdx.x;
    const int cg  = tid >> 1;                // channel 0..127
    const int sq  = tid & 1;                 // sample-quad (0..1)
    const int s0  = sq * 4;
    const int wv  = tid >> 6;                // wave 0..3
    const int sbase = blockIdx.x * SPB + s0;

    // ---- stage first KL4 k4-chunks of W into LDS (once)
    if (TR) {
        const v4f* wt4 = (const v4f*)wt;
        for (int i = tid; i < 3 * KL4 * NHID; i += BS) {
            const int g = i / (KL4 * NHID);
            const int r = i - g * (KL4 * NHID);
            slds[i] = wt4[g * 4096 + r];
        }
    }
    for (int i = tid; i < 2 * NHID * SPB; i += BS) (&hsm[0][0][0])[i] = 0.0f;
    __syncthreads();

    const float brz = gb[384 + cg];
    const float brr = gb[384 + 128 + cg];
    const float brh = gb[384 + 256 + cg];
    const float xzI = gb[cg],       xz0c = xzI + gk[cg],       xz1c = xzI + gk[384 + cg];
    const float xrI = gb[128 + cg], xr0c = xrI + gk[128 + cg], xr1c = xrI + gk[384 + 128 + cg];
    const float xhI = gb[256 + cg], xh0c = xhI + gk[256 + cg], xh1c = xhI + gk[384 + 256 + cg];
    const float dwc0 = dw[cg * 2], dwc1 = dw[cg * 2 + 1];
    const float db0 = db[0], db1 = db[1];

    const v4f* lz = slds + cg;                     // LDS planes
    const v4f* lr = slds + KL4 * 128 + cg;
    const v4f* lh = slds + 2 * KL4 * 128 + cg;
    const v4f* wz4 = (const v4f*)wt + cg;          // global planes
    const v4f* wr4 = (const v4f*)wt + 4096 + cg;
    const v4f* wh4 = (const v4f*)wt + 8192 + cg;
    const float* rkp = rk + cg;                    // fallback

    int   pv[4] = {0, 0, 0, 0};
    float lg[4] = {0.f, 0.f, 0.f, 0.f};
    float pr[4] = {1.f, 1.f, 1.f, 1.f};            // 8-step psel product
    int cur = 0;

    for (int t = 0; t < NSTEPS; ++t) {
        // prefetch this step's u (consumed after barrier; L1-resident rows)
        float uv[4];
        #pragma unroll
        for (int j = 0; j < 4; ++j)
            uv[j] = u[(size_t)(sbase + j) * NSTEPS + t];

        v2f az01 = {brz, brz}, az23 = {brz, brz};
        v2f ar01 = {brr, brr}, ar23 = {brr, brr};
        v2f ah01 = {brh, brh}, ah23 = {brh, brh};
        const float* hb = &hsm[cur][0][0];

#define GEMM_K4(WZ, WR, WH, K4) do {                                      \
    const v4f h0 = *(const v4f*)(hb + (4*(K4)+0)*SPB + s0);               \
    const v4f h1 = *(const v4f*)(hb + (4*(K4)+1)*SPB + s0);               \
    const v4f h2 = *(const v4f*)(hb + (4*(K4)+2)*SPB + s0);               \
    const v4f h3 = *(const v4f*)(hb + (4*(K4)+3)*SPB + s0);               \
    const v2f wzA = (WZ).xy, wzB = (WZ).zw;                               \
    const v2f wrA = (WR).xy, wrB = (WR).zw;                               \
    const v2f whA = (WH).xy, whB = (WH).zw;                               \
    PK_LO(az01, wzA, h0.xy); PK_LO(az23, wzA, h0.zw);                     \
    PK_LO(ar01, wrA, h0.xy); PK_LO(ar23, wrA, h0.zw);                     \
    PK_LO(ah01, whA, h0.xy); PK_LO(ah23, whA, h0.zw);                     \
    PK_HI(az01, wzA, h1.xy); PK_HI(az23, wzA, h1.zw);                     \
    PK_HI(ar01, wrA, h1.xy); PK_HI(ar23, wrA, h1.zw);                     \
    PK_HI(ah01, whA, h1.xy); PK_HI(ah23, whA, h1.zw);                     \
    PK_LO(az01, wzB, h2.xy); PK_LO(az23, wzB, h2.zw);                     \
    PK_LO(ar01, wrB, h2.xy); PK_LO(ar23, wrB, h2.zw);                     \
    PK_LO(ah01, whB, h2.xy); PK_LO(ah23, whB, h2.zw);                     \
    PK_HI(az01, wzB, h3.xy); PK_HI(az23, wzB, h3.zw);                     \
    PK_HI(ar01, wrB, h3.xy); PK_HI(ar23, wrB, h3.zw);                     \
    PK_HI(ah01, whB, h3.xy); PK_HI(ah23, whB, h3.zw);                     \
} while (0)

        if (TR) {
            #pragma unroll 4
            for (int k4 = 0; k4 < KL4; ++k4) {        // LDS-resident chunk
                const v4f wz = lz[k4 * 128];
                const v4f wr = lr[k4 * 128];
                const v4f wh = lh[k4 * 128];
                GEMM_K4(wz, wr, wh, k4);
            }
            #pragma unroll 4
            for (int k4 = KL4; k4 < 32; ++k4) {       // global chunk (L1-hit)
                const v4f wz = wz4[k4 * 128];
                const v4f wr = wr4[k4 * 128];
                const v4f wh = wh4[k4 * 128];
                GEMM_K4(wz, wr, wh, k4);
            }
        } else {
            const float* wp = rkp;
            #pragma unroll 4
            for (int k = 0; k < NHID; ++k) {
                const float wzs = wp[0];
                const float wrs = wp[NHID];
                const float whs = wp[2 * NHID];
                const v4f hv = *(const v4f*)(hb + k * SPB + s0);
                const float hk[4] = {hv.x, hv.y, hv.z, hv.w};
                float azs[4] = {az01.x, az01.y, az23.x, az23.y};
                float ars[4] = {ar01.x, ar01.y, ar23.x, ar23.y};
                float ahs[4] = {ah01.x, ah01.y, ah23.x, ah23.y};
                #pragma unroll
                for (int j = 0; j < 4; ++j) azs[j] = fmaf(wzs, hk[j], azs[j]);
                #pragma unroll
                for (int j = 0; j < 4; ++j) ars[j] = fmaf(wrs, hk[j], ars[j]);
                #pragma unroll
                for (int j = 0; j < 4; ++j) ahs[j] = fmaf(whs, hk[j], ahs[j]);
                az01 = (v2f){azs[0], azs[1]}; az23 = (v2f){azs[2], azs[3]};
                ar01 = (v2f){ars[0], ars[1]}; ar23 = (v2f){ars[2], ars[3]};
                ah01 = (v2f){ahs[0], ahs[1]}; ah23 = (v2f){ahs[2], ahs[3]};
                wp += 3 * NHID;
            }
        }
#undef GEMM_K4

        const float az[4] = {az01.x, az01.y, az23.x, az23.y};
        const float ar[4] = {ar01.x, ar01.y, ar23.x, ar23.y};
        const float ah[4] = {ah01.x, ah01.y, ah23.x, ah23.y};

        // ---- gates + state update
        const v4f ho = *(const v4f*)(hb + cg * SPB + s0);
        const float hov[4] = {ho.x, ho.y, ho.z, ho.w};
        float hn[4], p0s[4], p1s[4];
        #pragma unroll
        for (int j = 0; j < 4; ++j) {
            float xz = pv[j] ? xz1c : xz0c;
            float xr = pv[j] ? xr1c : xr0c;
            float xh = pv[j] ? xh1c : xh0c;
            if (t == 0) { xz = xzI; xr = xrI; xh = xhI; }
            const float z  = 1.0f / (1.0f + expf(-(xz + az[j])));
            const float r  = 1.0f / (1.0f + expf(-(xr + ar[j])));
            const float hc = tanhf(xh + r * ah[j]);
            const float hnew = z * hov[j] + (1.0f - z) * hc;
            hn[j] = hnew;
            p0s[j] = hnew * dwc0;
            p1s[j] = hnew * dwc1;
        }
        *(v4f*)&hsm[cur ^ 1][cg][s0] = (v4f){hn[0], hn[1], hn[2], hn[3]};

        // butterfly over the wave's 32 channels (ch bits at lane bits 1..5):
        // xor lane 2,4,8,16 via ds_swizzle, xor 32 via shfl
        #pragma unroll
        for (int j = 0; j < 4; ++j) {
            p0s[j] += swz<0x081F>(p0s[j]);  p1s[j] += swz<0x081F>(p1s[j]);
            p0s[j] += swz<0x101F>(p0s[j]);  p1s[j] += swz<0x101F>(p1s[j]);
            p0s[j] += swz<0x201F>(p0s[j]);  p1s[j] += swz<0x201F>(p1s[j]);
            p0s[j] += swz<0x401F>(p0s[j]);  p1s[j] += swz<0x401F>(p1s[j]);
            p0s[j] += __shfl_xor(p0s[j], 32);
            p1s[j] += __shfl_xor(p1s[j], 32);
        }
        const int pb = t & 1;
        if ((tid & 63) < 2) {
            *(float4*)&part[pb][wv][sq][0] = make_float4(p0s[0], p0s[1], p0s[2], p0s[3]);
            *(float4*)&part[pb][wv][sq][4] = make_float4(p1s[0], p1s[1], p1s[2], p1s[3]);
        }
        __syncthreads();   // single barrier: h_new + partials visible

        // ---- redundant logit/sample phase: every thread, its own 4 samples
        float l0[4] = {db0, db0, db0, db0};
        float l1[4] = {db1, db1, db1, db1};
        #pragma unroll
        for (int w = 0; w < 4; ++w) {            // wave-ascending fold
            const float4 a = *(const float4*)&part[pb][w][sq][0];
            const float4 b = *(const float4*)&part[pb][w][sq][4];
            l0[0] += a.x; l0[1] += a.y; l0[2] += a.z; l0[3] += a.w;
            l1[0] += b.x; l1[1] += b.y; l1[2] += b.z; l1[3] += b.w;
        }
        #pragma unroll
        for (int j = 0; j < 4; ++j) {
            const float mx = fmaxf(l0[j], l1[j]);
            const float e0 = expf(l0[j] - mx);
            const float e1 = expf(l1[j] - mx);
            const float inv = 1.0f / (e0 + e1);
            const float p1v = e1 * inv;
            const int st = (uv[j] < p1v) ? 1 : 0;
            const float psel = st ? p1v : (e0 * inv);
            pr[j] *= (psel + 1e-10f);
            pv[j] = st;
            if (cg == 0)
                out[(size_t)(sbase + j) * NSTEPS + t] = (float)st;
        }
        if ((t & 7) == 7) {     // batched log
            #pragma unroll
            for (int j = 0; j < 4; ++j) { lg[j] += logf(pr[j]); pr[j] = 1.0f; }
        }
        cur ^= 1;
    }

    if (cg == 0) {
        #pragma unroll
        for (int j = 0; j < 4; ++j)
            out[SAMP_ELEMS + sbase + j] = lg[j];
    }
}

extern "C" void kernel_launch(void* const* d_in, const int* in_sizes, int n_in,
                              void* d_out, int out_size, void* d_ws, size_t ws_size,
                              hipStream_t stream) {
    const float* gk = (const float*)d_in[0];
    const float* rk = (const float*)d_in[1];
    const float* gb = (const float*)d_in[2];
    const float* dw = (const float*)d_in[3];
    const float* db = (const float*)d_in[4];
    const float* u  = (const float*)d_in[5];
    float* out = (float*)d_out;

    if (ws_size >= (size_t)WT_ELEMS * sizeof(float)) {
        float* wt = (float*)d_ws;
        pack_w_kernel<<<(WT_ELEMS + 255) / 256, 256, 0, stream>>>(rk, wt);
        vmc_gru_kernel<1><<<NBLK, BS, 0, stream>>>(gk, rk, gb, dw, db, u, wt, out);
    } else {
        vmc_gru_kernel<0><<<NBLK, BS, 0, stream>>>(gk, rk, gb, dw, db, u, rk, out);
    }
}